// Round 9
// baseline (73.012 us; speedup 1.0000x reference)
//
#include <hip/hip_runtime.h>
#include <hip/hip_bf16.h>

#define KS    21
#define H     192
#define W     192
#define OH    172
#define OW    172
#define CROP  10
#define PLANE (H*W)

#define NCHUNK 7
#define CROWS  3                       // kernel rows per chunk (7*3=21)

#define TXD   96                      // covers full width: kraw cols 2*tx,2*tx+1
#define TYD   4                       // output rows per block (172 = 43*4, no tail)
#define NTHR  (TXD*TYD)               // 384 threads = 6 waves
#define SROWS (TYD + CROWS - 1)       // 6 staged input rows
#define SCH   (W/2)                   // 96 float4 per parity per row

#define CS    (OH * OW)                // 29584
#define OUTN  (4 * 4 * OH * OW)        // one partial span = 473344 floats

__device__ __forceinline__ float softplusf_(float x) {
    // stable: max(x,0) + log(1 + exp(-|x|))
    float e = __expf(-fabsf(x));
    return fmaxf(x, 0.0f) + __logf(1.0f + e);
}

// issue one kraw row's 21 float2 loads (per lane) into registers.
// ALL lanes load: lanes tx<5 / tx>90 fetch bytes that keep each
// (tap, 4-row) chunk a single contiguous 3KB DRAM stream (R8 lesson:
// scattered 128B granules cap read BW at ~4.2 TB/s).
#define LOADROW(buf, irow) do {                                              \
    const float* kp_ = kb + (size_t)((i0 + (irow)) * KS) * PLANE;            \
    _Pragma("unroll")                                                        \
    for (int j = 0; j < KS; ++j)                                             \
        (buf)[j] = *reinterpret_cast<const float2*>(kp_ + (size_t)j * PLANE);\
} while (0)

// consume one row: softplus + mask + accumulate, rolling LDS window.
// window cols (image coords) x0..x0+21, x0 = 2*txc-10 (clamped for edge lanes)
#define COMPROW(buf) do {                                                    \
    float4 cur_ = s4[0][rrw][txc - 5];                                       \
    _Pragma("unroll")                                                        \
    for (int j = 0; j < KS; ++j) {                                           \
        float4 nxt_ = s4[(j + 1) & 1][rrw][txc - 5 + ((j + 1) >> 1)];        \
        float s0_ = softplusf_((buf)[j].x);                                  \
        float s1_ = softplusf_((buf)[j].y);                                  \
        float km0_ = s0_ * cur_.x;                                           \
        float km1_ = s1_ * nxt_.x;                                           \
        ks0 += km0_;                                                         \
        ks1 += km1_;                                                         \
        a00 = fmaf(km0_, cur_.y, a00);  a01 = fmaf(km1_, nxt_.y, a01);       \
        a10 = fmaf(km0_, cur_.z, a10);  a11 = fmaf(km1_, nxt_.z, a11);       \
        a20 = fmaf(km0_, cur_.w, a20);  a21 = fmaf(km1_, nxt_.w, a21);       \
        cur_ = nxt_;                                                         \
    }                                                                        \
} while (0)

// 3 waves/EU (<=170 VGPR); ~130 live incl. 84 kv-buffer regs -> slack so the
// compiler keeps bursts hoisted (R4 lesson)
__global__ __launch_bounds__(NTHR, 3)
void ar_partial_kernel(const float* __restrict__ kraw,
                       const float* __restrict__ rad,
                       const float* __restrict__ mask,
                       float* __restrict__ part)
{
    // {mask, r, g, b} per pixel, column-parity split: 16B-stride lane reads
    __shared__ float4 s4[2][SROWS][SCH];

    const int zz    = blockIdx.y;          // 4*NCHUNK = 28
    const int b     = zz & 3;
    const int chunk = zz >> 2;
    const int i0    = chunk * CROWS;

    const int y0t = blockIdx.x * TYD;      // 43 y-tiles, no remainder
    const int tx  = threadIdx.x;           // 0..95
    const int ty  = threadIdx.y;           // 0..3
    const int tid = ty * TXD + tx;

    // ---- stage mask+radiance rows [y0t+i0 .. y0t+i0+5], full width.
    // Row range max = 168+18+5 = 191, cols 0..191: no clamping needed.
    const float* mbase = mask + (size_t)b * PLANE;
    const float* rbase = rad  + (size_t)b * 3 * PLANE;
    #pragma unroll
    for (int t = tid; t < SROWS * W; t += NTHR) {
        int rr = t / W, cc = t - rr * W;
        int off = (y0t + i0 + rr) * W + cc;
        float4 v;
        v.x = mbase[off];
        v.y = rbase[off];
        v.z = rbase[off + PLANE];
        v.w = rbase[off + 2 * PLANE];
        s4[cc & 1][rr][cc >> 1] = v;
    }
    __syncthreads();

    const int y   = y0t + ty;              // 0..171 always valid
    const int txc = min(max(tx, 5), 90);   // clamp window base for edge lanes
    const int x0  = 2 * tx - CROP;         // output col; valid iff 5<=tx<=90
    const int rrw = ty;                    // LDS row for this thread's window
                                           // (input row y+i0+i -> staged row ty+i;
                                           //  handled by COMPROW using rrw+i below)

    // kraw base: col 2*tx (0..190), row y+CROP (10..181) — always in-plane
    const float* kb = kraw + (size_t)b * KS * KS * PLANE
                           + (size_t)(y + CROP) * W + 2 * tx;

    float ks0 = 0.f, ks1 = 0.f;
    float a00 = 0.f, a01 = 0.f;
    float a10 = 0.f, a11 = 0.f;
    float a20 = 0.f, a21 = 0.f;

    // 2-row software pipeline (R3/R7 proven): up to 42 loads in flight
    float2 kva[KS], kvb[KS];
    {
        LOADROW(kva, 0);
        LOADROW(kvb, 1);
        { const int rrw2 = ty + 0; const int rrw = rrw2; COMPROW(kva); }
        LOADROW(kva, 2);
        { const int rrw2 = ty + 1; const int rrw = rrw2; COMPROW(kvb); }
        { const int rrw2 = ty + 2; const int rrw = rrw2; COMPROW(kva); }
    }

    // ---- store partial (layout mirrors final out, offset chunk*OUTN) ----
    if (tx >= 5 && tx <= 90) {             // x0 in [0,170], even
        float* pb = part + (size_t)chunk * OUTN;
        const size_t wbase = ((size_t)b * 3 * OH + y) * OW + x0;
        const size_t kbase = (size_t)12 * CS + ((size_t)b * OH + y) * OW + x0;
        *reinterpret_cast<float2*>(pb + wbase)          = make_float2(a00, a01);
        *reinterpret_cast<float2*>(pb + wbase + CS)     = make_float2(a10, a11);
        *reinterpret_cast<float2*>(pb + wbase + 2 * CS) = make_float2(a20, a21);
        *reinterpret_cast<float2*>(pb + kbase)          = make_float2(ks0, ks1);
    }
}

__global__ __launch_bounds__(256)
void ar_reduce_kernel(const float* __restrict__ part, float* __restrict__ out)
{
    int i = blockIdx.x * 256 + threadIdx.x;      // over OUTN/4 float4s
    if (i < OUTN / 4) {
        const float4* p4 = reinterpret_cast<const float4*>(part);
        float4 r = p4[i];
        #pragma unroll
        for (int k = 1; k < NCHUNK; ++k) {
            float4 v = p4[i + (size_t)k * (OUTN / 4)];
            r.x += v.x; r.y += v.y; r.z += v.z; r.w += v.w;
        }
        reinterpret_cast<float4*>(out)[i] = r;
    }
}

extern "C" void kernel_launch(void* const* d_in, const int* in_sizes, int n_in,
                              void* d_out, int out_size, void* d_ws, size_t ws_size,
                              hipStream_t stream) {
    const float* kraw = (const float*)d_in[0];   // [4,441,192,192] f32
    const float* rad  = (const float*)d_in[1];   // [4,3,192,192]   f32
    const float* mask = (const float*)d_in[2];   // [4,1,192,192]   f32
    float* out  = (float*)d_out;                 // ws[4,3,172,172] ++ ks[4,1,172,172]
    float* part = (float*)d_ws;                  // NCHUNK partials of OUTN floats

    dim3 block(TXD, TYD, 1);
    dim3 grid(OH / TYD, 4 * NCHUNK, 1);          // 43 x 28 = 1204 blocks
    hipLaunchKernelGGL(ar_partial_kernel, grid, block, 0, stream,
                       kraw, rad, mask, part);

    int n4 = OUTN / 4;
    hipLaunchKernelGGL(ar_reduce_kernel, dim3((n4 + 255) / 256), dim3(256), 0, stream,
                       part, out);
}